// Round 1
// baseline (317.023 us; speedup 1.0000x reference)
//
#include <hip/hip_runtime.h>
#include <hip/hip_bf16.h>

#define BATCH 2
#define SEQ 2048
#define HIDDIM 2048
#define NHEADS 16
#define HDIM 128

typedef __attribute__((ext_vector_type(8))) short bf16x8;
typedef __attribute__((ext_vector_type(4))) short short4v;
typedef __attribute__((ext_vector_type(4))) float f32x4;

__device__ __forceinline__ short f2bf(float f) {
  unsigned u = __builtin_bit_cast(unsigned, f);
  unsigned r = (u + 0x7fffu + ((u >> 16) & 1u)) >> 16;
  return (short)r;
}

__device__ __forceinline__ void gl_lds16(const void* g, void* l) {
  __builtin_amdgcn_global_load_lds(
      (const __attribute__((address_space(1))) void*)g,
      (__attribute__((address_space(3))) void*)l, 16, 0, 0);
}

// ---- f32 -> bf16 cast, 4 elems/thread ----
__global__ void cvt_kernel(const float* __restrict__ in, short* __restrict__ out, int n) {
  int i = (blockIdx.x * blockDim.x + threadIdx.x) * 4;
  if (i >= n) return;
  float4 v = *(const float4*)(in + i);
  short4v o;
  o[0] = f2bf(v.x); o[1] = f2bf(v.y); o[2] = f2bf(v.z); o[3] = f2bf(v.w);
  *(short4v*)(out + i) = o;
}

// ---- C[M,N] = A[M,K] @ W[N,K]^T + bias.
// MODE 0: f32 C (row*N+col), MODE 1: bf16 C (row*N+col), MODE 2: bf16 C transposed (col*M+row)
// LDS tiles [128][64] bf16, XOR-swizzled in 16B groups: phys_cg = cg ^ (row&7).
template <int MODE>
__global__ __launch_bounds__(256, 2)
void gemm_bt(const short* __restrict__ A, const short* __restrict__ W,
             const float* __restrict__ bias, void* __restrict__ Cv,
             int M, int N, int K, long sA, long sC)
{
  __shared__ short As[128 * 64];
  __shared__ short Ws[128 * 64];
  const int tid = threadIdx.x;
  const int lane = tid & 63;
  const int w = tid >> 6;
  const int wr = w >> 1, wc = w & 1;
  const int tm = blockIdx.y * 128, tn = blockIdx.x * 128;
  const short* Ap = A + (size_t)blockIdx.z * sA;

  const int rA = lane & 15;
  const int r7 = rA & 7;
  const int srow = lane >> 3;            // 0..7 (row within 1KB chunk, rows are 128B)
  const int scg  = (lane & 7) ^ srow;    // pre-swizzled source 16B-group

  f32x4 acc[4][4] = {};

  for (int k0 = 0; k0 < K; k0 += 64) {
    __syncthreads();
#pragma unroll
    for (int i = 0; i < 4; ++i) {
      int ch = w * 4 + i;                // 16 chunks of 1KB per tile
      gl_lds16(Ap + (size_t)(tm + ch * 8 + srow) * K + k0 + scg * 8, As + ch * 512);
      gl_lds16(W  + (size_t)(tn + ch * 8 + srow) * K + k0 + scg * 8, Ws + ch * 512);
    }
    __syncthreads();
#pragma unroll
    for (int kk = 0; kk < 64; kk += 32) {
      const int cg = (kk >> 3) + (lane >> 4);
      const int co = ((cg ^ r7) << 3);
      bf16x8 af[4];
#pragma unroll
      for (int mi = 0; mi < 4; ++mi)
        af[mi] = *(const bf16x8*)(As + ((wr * 64 + mi * 16 + rA) << 6) + co);
#pragma unroll
      for (int ni = 0; ni < 4; ++ni) {
        bf16x8 wf = *(const bf16x8*)(Ws + ((wc * 64 + ni * 16 + rA) << 6) + co);
#pragma unroll
        for (int mi = 0; mi < 4; ++mi)
          acc[mi][ni] = __builtin_amdgcn_mfma_f32_16x16x32_bf16(af[mi], wf, acc[mi][ni], 0, 0, 0);
      }
    }
  }

  const int cr = (lane >> 4) * 4;
  const int cc = lane & 15;
#pragma unroll
  for (int ni = 0; ni < 4; ++ni) {
    int col = tn + wc * 64 + ni * 16 + cc;
    float bv = bias[col];
#pragma unroll
    for (int mi = 0; mi < 4; ++mi) {
#pragma unroll
      for (int r = 0; r < 4; ++r) {
        int row = tm + wr * 64 + mi * 16 + cr + r;
        float v = acc[mi][ni][r] + bv;
        if constexpr (MODE == 0)
          ((float*)Cv)[(size_t)blockIdx.z * sC + (size_t)row * N + col] = v;
        else if constexpr (MODE == 1)
          ((short*)Cv)[(size_t)row * N + col] = f2bf(v);
        else
          ((short*)Cv)[(size_t)col * M + row] = f2bf(v);
      }
    }
  }
}

// ---- fused multi-query attention (no mask: contribution <= 1e-9) ----
// grid (qtile=16, head=16, batch=2), 256 threads. Q[4096][2048] bf16,
// K[4096][128] bf16, Vt[128][4096] bf16. Writes OT[b][h*128+d][s] bf16.
__global__ __launch_bounds__(256, 2)
void attn_kernel(const short* __restrict__ Q, const short* __restrict__ Kp,
                 const short* __restrict__ Vt, short* __restrict__ OT)
{
  __shared__ short smem[32768];           // Ks [128][128] | Vs [128][128]; Ps aliases Ks; Ot aliases smem
  short* Ks = smem;
  short* Vs = smem + 16384;

  const int tid = threadIdx.x;
  const int lane = tid & 63;
  const int w = tid >> 6;
  const int b = blockIdx.z, h = blockIdx.y, qt = blockIdx.x;
  const int rA = lane & 15;
  const int r7 = rA & 7;
  const int hi4 = lane >> 4;              // 0..3
  const int cr = hi4 * 4;
  const int cc = rA;
  const float RS = 0.08838834764831845f;  // 1/sqrt(128)

  // Q fragments held in registers for the whole block (wave w owns q rows w*32..w*32+31)
  bf16x8 qf[2][4];
  {
    const short* Qp = Q + ((size_t)(b * SEQ + qt * 128)) * HIDDIM + h * HDIM;
#pragma unroll
    for (int mi = 0; mi < 2; ++mi)
#pragma unroll
      for (int kk = 0; kk < 4; ++kk)
        qf[mi][kk] = *(const bf16x8*)(Qp + (size_t)(w * 32 + mi * 16 + rA) * HIDDIM + kk * 32 + hi4 * 8);
  }

  f32x4 o[2][8] = {};
  float mrow[2][4], lrow[2][4];
#pragma unroll
  for (int mi = 0; mi < 2; ++mi)
#pragma unroll
    for (int r = 0; r < 4; ++r) { mrow[mi][r] = -1e30f; lrow[mi][r] = 0.f; }

  for (int c = 0; c < 16; ++c) {
    __syncthreads();                      // prior PV reads of Vs/Ps done before restage
    // stage K chunk [128 kv][128 d] and V^T chunk [128 d][128 kv]; rows are 256B = 16 groups.
#pragma unroll
    for (int i = 0; i < 8; ++i) {
      int ch = w * 8 + i;                 // 0..31, 4 rows per 1KB chunk
      int rowp = ch * 4 + hi4;
      int rr = rowp & 7;                  // = (ch&1)*4 + hi4
      int cgl = rA ^ rr;                  // pre-swizzled source group
      gl_lds16(Kp + ((size_t)(b * SEQ + c * 128 + rowp)) * HDIM + cgl * 8, Ks + ch * 512);
      gl_lds16(Vt + (size_t)rowp * (BATCH * SEQ) + b * SEQ + c * 128 + cgl * 8, Vs + ch * 512);
    }
    __syncthreads();

    // QK^T : s[mi][ni] rows = q, cols = kv
    f32x4 s[2][8] = {};
#pragma unroll
    for (int ni = 0; ni < 8; ++ni) {
#pragma unroll
      for (int kk = 0; kk < 4; ++kk) {
        int cg = kk * 4 + hi4;
        bf16x8 kf = *(const bf16x8*)(Ks + ((ni * 16 + rA) << 7) + ((cg ^ r7) << 3));
#pragma unroll
        for (int mi = 0; mi < 2; ++mi)
          s[mi][ni] = __builtin_amdgcn_mfma_f32_16x16x32_bf16(qf[mi][kk], kf, s[mi][ni], 0, 0, 0);
      }
    }
#pragma unroll
    for (int mi = 0; mi < 2; ++mi)
#pragma unroll
      for (int ni = 0; ni < 8; ++ni) s[mi][ni] *= RS;

    __syncthreads();                      // all waves done reading Ks; Ps aliases Ks
    short* Ps = smem;

    // online softmax (rows spread over 16-lane groups: xor 1,2,4,8 reduce)
#pragma unroll
    for (int mi = 0; mi < 2; ++mi) {
      float corr[4], rsum[4];
#pragma unroll
      for (int r = 0; r < 4; ++r) {
        float mx = s[mi][0][r];
#pragma unroll
        for (int ni = 1; ni < 8; ++ni) mx = fmaxf(mx, s[mi][ni][r]);
#pragma unroll
        for (int d = 1; d < 16; d <<= 1) mx = fmaxf(mx, __shfl_xor(mx, d));
        float mold = mrow[mi][r];
        float mnew = fmaxf(mold, mx);
        float cf = __expf(mold - mnew);
        mrow[mi][r] = mnew;
        lrow[mi][r] *= cf;
        corr[r] = cf;
        rsum[r] = 0.f;
      }
#pragma unroll
      for (int ni = 0; ni < 8; ++ni)
#pragma unroll
        for (int r = 0; r < 4; ++r) o[mi][ni][r] *= corr[r];
#pragma unroll
      for (int ni = 0; ni < 8; ++ni) {
#pragma unroll
        for (int r = 0; r < 4; ++r) {
          float p = __expf(s[mi][ni][r] - mrow[mi][r]);
          rsum[r] += p;
          int q = w * 32 + mi * 16 + cr + r;
          int kv = ni * 16 + cc;
          Ps[(q << 7) + (((kv >> 3) ^ (q & 7)) << 3) + (kv & 7)] = f2bf(p);
        }
      }
#pragma unroll
      for (int r = 0; r < 4; ++r) {
        float t = rsum[r];
#pragma unroll
        for (int d = 1; d < 16; d <<= 1) t += __shfl_xor(t, d);
        lrow[mi][r] += t;
      }
    }

    // PV : o[q][d] += P[q][kv] * V[kv][d]  (A from Ps own rows, B from Vs = V^T chunk)
#pragma unroll
    for (int kk = 0; kk < 4; ++kk) {
      int cg = kk * 4 + hi4;
      int co = ((cg ^ r7) << 3);
      bf16x8 pf[2];
#pragma unroll
      for (int mi = 0; mi < 2; ++mi)
        pf[mi] = *(const bf16x8*)(Ps + ((w * 32 + mi * 16 + rA) << 7) + co);
#pragma unroll
      for (int ni = 0; ni < 8; ++ni) {
        bf16x8 vf = *(const bf16x8*)(Vs + ((ni * 16 + rA) << 7) + co);
#pragma unroll
        for (int mi = 0; mi < 2; ++mi)
          o[mi][ni] = __builtin_amdgcn_mfma_f32_16x16x32_bf16(pf[mi], vf, o[mi][ni], 0, 0, 0);
      }
    }
  }

  // epilogue: normalize, transpose via padded LDS, coalesced write of OT[h*128+d][q]
  __syncthreads();
  short* Ot = smem;                       // [128][136] padded (17408 shorts < 32768)
#pragma unroll
  for (int mi = 0; mi < 2; ++mi)
#pragma unroll
    for (int r = 0; r < 4; ++r) {
      float inv = 1.f / lrow[mi][r];
      int q = w * 32 + mi * 16 + cr + r;
#pragma unroll
      for (int ni = 0; ni < 8; ++ni) {
        int d = ni * 16 + cc;
        Ot[d * 136 + q] = f2bf(o[mi][ni][r] * inv);
      }
    }
  __syncthreads();
  {
    short* dst = OT + (size_t)b * (SEQ * HIDDIM) + (size_t)(h * HDIM) * SEQ + qt * 128;
#pragma unroll
    for (int pass = 0; pass < 8; ++pass) {
      int d = pass * 16 + (tid >> 4);
      int q0 = (tid & 15) * 8;
      *(bf16x8*)(dst + (size_t)d * SEQ + q0) = *(const bf16x8*)(Ot + d * 136 + q0);
    }
  }
}

extern "C" void kernel_launch(void* const* d_in, const int* in_sizes, int n_in,
                              void* d_out, int out_size, void* d_ws, size_t ws_size,
                              hipStream_t stream)
{
  const float* hidden = (const float*)d_in[0];
  // d_in[1] = attention_mask : unused (scaled by -1e-9 in reference, negligible)
  const float* Wq = (const float*)d_in[2];
  const float* bq = (const float*)d_in[3];
  const float* Wk = (const float*)d_in[4];
  const float* bk = (const float*)d_in[5];
  const float* Wv = (const float*)d_in[6];
  const float* bv = (const float*)d_in[7];
  const float* Wo = (const float*)d_in[8];
  const float* bo = (const float*)d_in[9];
  float* out = (float*)d_out;

  // workspace layout (shorts). OT aliases h_bf (h dead after V projection).
  short* ws    = (short*)d_ws;
  short* Wq_bf = ws;                       // 4194304
  short* Wk_bf = Wq_bf + 4194304;          // 262144
  short* Wv_bf = Wk_bf + 262144;           // 262144
  short* Wo_bf = Wv_bf + 262144;           // 4194304
  short* Q_bf  = Wo_bf + 4194304;          // 8388608
  short* K_bf  = Q_bf + 8388608;           // 524288
  short* Vt_bf = K_bf + 524288;            // 524288
  short* h_bf  = Vt_bf + 524288;           // 8388608
  short* OT    = h_bf;                     // alias

  cvt_kernel<<<8192, 256, 0, stream>>>(hidden, h_bf, 8388608);
  cvt_kernel<<<4096, 256, 0, stream>>>(Wq, Wq_bf, 4194304);
  cvt_kernel<<<256,  256, 0, stream>>>(Wk, Wk_bf, 262144);
  cvt_kernel<<<256,  256, 0, stream>>>(Wv, Wv_bf, 262144);
  cvt_kernel<<<4096, 256, 0, stream>>>(Wo, Wo_bf, 4194304);

  // Q = h @ Wq^T + bq  -> bf16 [4096][2048]
  gemm_bt<1><<<dim3(16, 32, 1), 256, 0, stream>>>(h_bf, Wq_bf, bq, Q_bf, 4096, 2048, 2048, 0, 0);
  // K = h @ Wk^T + bk  -> bf16 [4096][128]
  gemm_bt<1><<<dim3(1, 32, 1), 256, 0, stream>>>(h_bf, Wk_bf, bk, K_bf, 4096, 128, 2048, 0, 0);
  // V^T = (h @ Wv^T + bv)^T -> bf16 [128][4096]
  gemm_bt<2><<<dim3(1, 32, 1), 256, 0, stream>>>(h_bf, Wv_bf, bv, Vt_bf, 4096, 128, 2048, 0, 0);
  // attention -> OT[b][h*128+d][s] bf16
  attn_kernel<<<dim3(16, 16, 2), 256, 0, stream>>>(Q_bf, K_bf, Vt_bf, OT);
  // out[b] = OT[b] @ Wo^T + bo -> f32 (reference's reshape quirk: contraction over s)
  gemm_bt<0><<<dim3(16, 16, 2), 256, 0, stream>>>(OT, Wo_bf, bo, out, 2048, 2048, 2048,
                                                  4194304, 4194304);
}